// Round 1
// baseline (472.041 us; speedup 1.0000x reference)
//
#include <hip/hip_runtime.h>
#include <stdint.h>

#define DM 1024
#define DFF 4096
#define NH 16
#define DH 64
#define SEQ 2048
#define MROWS 4096  // B*S

typedef unsigned short u16;
typedef __attribute__((ext_vector_type(8))) short bf16x8;
typedef __attribute__((ext_vector_type(4))) float f32x4;
typedef __attribute__((ext_vector_type(4))) unsigned short u16x4;

__device__ __forceinline__ u16 f2b(float f) {
  union { float f; uint32_t u; } v; v.f = f;
  uint32_t r = v.u + 0x7FFFu + ((v.u >> 16) & 1u);
  return (u16)(r >> 16);
}

__device__ __forceinline__ void gl_lds16(const void* g, void* l) {
  __builtin_amdgcn_global_load_lds(
      (const __attribute__((address_space(1))) uint32_t*)g,
      (__attribute__((address_space(3))) uint32_t*)l, 16, 0, 0);
}

// ---------------- weight fp32 -> bf16 convert (all 6 weights, one kernel) --
struct CvtArgs { const float* src[6]; u16* dst[6]; int n4[6]; };

__global__ void cvt_kernel(CvtArgs a) {
  const int stride = gridDim.x * blockDim.x;
  const int t0 = blockIdx.x * blockDim.x + threadIdx.x;
  for (int i = 0; i < 6; ++i) {
    const float4* s = (const float4*)a.src[i];
    u16x4* d = (u16x4*)a.dst[i];
    const int n = a.n4[i];
    for (int idx = t0; idx < n; idx += stride) {
      float4 v = s[idx];
      u16x4 o;
      o[0] = f2b(v.x); o[1] = f2b(v.y); o[2] = f2b(v.z); o[3] = f2b(v.w);
      d[idx] = o;
    }
  }
}

// ---------------- fused LayerNorm: fp32 in -> bf16 out ---------------------
__global__ __launch_bounds__(256)
void ln_kernel(const float* __restrict__ x, const float* __restrict__ g,
               const float* __restrict__ be, u16* __restrict__ out) {
  const int row = blockIdx.x;
  const int tid = threadIdx.x;
  const float4 v = ((const float4*)(x + (size_t)row * DM))[tid];
  float s  = v.x + v.y + v.z + v.w;
  float s2 = v.x * v.x + v.y * v.y + v.z * v.z + v.w * v.w;
  #pragma unroll
  for (int m = 1; m < 64; m <<= 1) {
    s  += __shfl_xor(s,  m, 64);
    s2 += __shfl_xor(s2, m, 64);
  }
  __shared__ float red[8];
  const int w = tid >> 6, lane = tid & 63;
  if (lane == 0) { red[w] = s; red[4 + w] = s2; }
  __syncthreads();
  s  = red[0] + red[1] + red[2] + red[3];
  s2 = red[4] + red[5] + red[6] + red[7];
  const float mu  = s * (1.0f / DM);
  const float var = s2 * (1.0f / DM) - mu * mu;
  const float rstd = rsqrtf(var + 1e-5f);
  const float4 gv = ((const float4*)g)[tid];
  const float4 bv = ((const float4*)be)[tid];
  u16x4 o;
  o[0] = f2b((v.x - mu) * rstd * gv.x + bv.x);
  o[1] = f2b((v.y - mu) * rstd * gv.y + bv.y);
  o[2] = f2b((v.z - mu) * rstd * gv.z + bv.z);
  o[3] = f2b((v.w - mu) * rstd * gv.w + bv.w);
  ((u16x4*)(out + (size_t)row * DM))[tid] = o;
}

// ---------------- GEMM: C[M,N] = A[M,K](bf16) * W[N,K](bf16)^T + bias ------
// EPI 0: -> bf16      EPI 1: +GELU(exact) -> bf16      EPI 2: +resid -> f32
struct GemmPtrs { const u16* W[3]; const float* bias[3]; void* out[3]; const float* resid; };

template<int EPI>
__global__ __launch_bounds__(256)
void gemm_bt(const u16* __restrict__ A, GemmPtrs p, int M, int N, int K) {
  __shared__ __align__(16) u16 As[128 * 64];
  __shared__ __align__(16) u16 Bs[128 * 64];
  const u16* __restrict__ Wm = p.W[blockIdx.z];
  const float* __restrict__ bias = p.bias[blockIdx.z];
  void* outv = p.out[blockIdx.z];
  const float* resid = p.resid;

  const int tid = threadIdx.x;
  const int lane = tid & 63;
  const int w = tid >> 6;
  const int brow = blockIdx.y * 128;
  const int bcol = blockIdx.x * 128;
  const int wr = (w >> 1) * 64, wc = (w & 1) * 64;

  f32x4 acc[4][4] = {};

  const int srow = lane >> 3;           // staging row within 8-row group
  const int scol = (lane & 7) * 8;      // staging col (bf16 elements)
  const int nkt = K >> 6;
  for (int kt = 0; kt < nkt; ++kt) {
    const int k0 = kt * 64;
    #pragma unroll
    for (int i = 0; i < 4; ++i) {
      const int r = i * 32 + w * 8;
      gl_lds16(&A [(size_t)(brow + r + srow) * K + k0 + scol], &As[r * 64]);
      gl_lds16(&Wm[(size_t)(bcol + r + srow) * K + k0 + scol], &Bs[r * 64]);
    }
    __syncthreads();
    #pragma unroll
    for (int ks = 0; ks < 2; ++ks) {
      const int ko = ks * 32 + (lane >> 4) * 8;
      bf16x8 a[4], b[4];
      #pragma unroll
      for (int f = 0; f < 4; ++f)
        a[f] = *(const bf16x8*)&As[(wr + f * 16 + (lane & 15)) * 64 + ko];
      #pragma unroll
      for (int f = 0; f < 4; ++f)
        b[f] = *(const bf16x8*)&Bs[(wc + f * 16 + (lane & 15)) * 64 + ko];
      #pragma unroll
      for (int fr = 0; fr < 4; ++fr)
        #pragma unroll
        for (int fc = 0; fc < 4; ++fc)
          acc[fr][fc] = __builtin_amdgcn_mfma_f32_16x16x32_bf16(a[fr], b[fc], acc[fr][fc], 0, 0, 0);
    }
    __syncthreads();
  }

  const int orow0 = brow + wr + (lane >> 4) * 4;
  const int ocol0 = bcol + wc + (lane & 15);
  #pragma unroll
  for (int fr = 0; fr < 4; ++fr) {
    #pragma unroll
    for (int fc = 0; fc < 4; ++fc) {
      const int col = ocol0 + fc * 16;
      const float bvv = bias[col];
      #pragma unroll
      for (int r = 0; r < 4; ++r) {
        const int row = orow0 + fr * 16 + r;
        const size_t idx = (size_t)row * N + col;
        float v = acc[fr][fc][r] + bvv;
        if (EPI == 0) {
          ((u16*)outv)[idx] = f2b(v);
        } else if (EPI == 1) {
          float ge = 0.5f * v * (1.0f + erff(v * 0.70710678118654752f));
          ((u16*)outv)[idx] = f2b(ge);
        } else {
          ((float*)outv)[idx] = v + resid[idx];
        }
      }
    }
  }
}

// ---------------- flash attention: bf16 q/k/v [B,S,H*DH] -> bf16 out -------
__global__ __launch_bounds__(256)
void attn_kernel(const u16* __restrict__ Q, const u16* __restrict__ K,
                 const u16* __restrict__ V, u16* __restrict__ O) {
  __shared__ __align__(16) u16 Ks[64 * 64];
  __shared__ __align__(16) u16 Vts[64 * 64];   // transposed: [d][key]
  __shared__ __align__(16) u16 Ps[4][16 * 64]; // per-wave P tile
  const int tid = threadIdx.x, lane = tid & 63, w = tid >> 6;
  const int bh = blockIdx.y, b = bh >> 4, h = bh & 15;
  const int q0 = blockIdx.x * 64 + w * 16;     // wave's q-row base in seq
  const size_t base = (size_t)b * SEQ * DM + (size_t)h * DH;

  // Q fragments (A-layout): row = lane&15, k = ks*32 + (lane>>4)*8
  bf16x8 qf[2];
  {
    const size_t qrow = base + (size_t)(q0 + (lane & 15)) * DM;
    #pragma unroll
    for (int ks = 0; ks < 2; ++ks)
      qf[ks] = *(const bf16x8*)&Q[qrow + ks * 32 + (lane >> 4) * 8];
  }

  f32x4 oacc[4] = {};
  float mrow[4], lrow[4];
  #pragma unroll
  for (int r = 0; r < 4; ++r) { mrow[r] = -1e30f; lrow[r] = 0.0f; }

  const int srow = lane >> 3, scol = (lane & 7) * 8;
  const int ko = (lane >> 4) * 8;

  for (int kt = 0; kt < SEQ / 64; ++kt) {
    // stage K tile (64x64) linear via global_load_lds
    #pragma unroll
    for (int i = 0; i < 2; ++i) {
      const int r = i * 32 + w * 8;
      gl_lds16(&K[base + (size_t)(kt * 64 + r + srow) * DM + scol], &Ks[r * 64]);
    }
    // stage V tile transposed (scalar ds writes)
    #pragma unroll
    for (int c = 0; c < 2; ++c) {
      const int idx = c * 256 + tid;
      const int s = idx >> 3, d0 = (idx & 7) * 8;
      bf16x8 vv = *(const bf16x8*)&V[base + (size_t)(kt * 64 + s) * DM + d0];
      #pragma unroll
      for (int j = 0; j < 8; ++j)
        Vts[(d0 + j) * 64 + s] = (u16)vv[j];
    }
    __syncthreads();

    // S = Q K^T  (scaled later)
    f32x4 sacc[4] = {};
    #pragma unroll
    for (int ks = 0; ks < 2; ++ks) {
      #pragma unroll
      for (int fn = 0; fn < 4; ++fn) {
        bf16x8 kb = *(const bf16x8*)&Ks[(fn * 16 + (lane & 15)) * 64 + ks * 32 + ko];
        sacc[fn] = __builtin_amdgcn_mfma_f32_16x16x32_bf16(qf[ks], kb, sacc[fn], 0, 0, 0);
      }
    }
    #pragma unroll
    for (int fn = 0; fn < 4; ++fn) sacc[fn] *= 0.125f;  // 1/sqrt(64)

    // online softmax update (rows r; 16-lane col-group reductions)
    #pragma unroll
    for (int r = 0; r < 4; ++r) {
      float tm = fmaxf(fmaxf(sacc[0][r], sacc[1][r]), fmaxf(sacc[2][r], sacc[3][r]));
      #pragma unroll
      for (int m = 1; m <= 8; m <<= 1) tm = fmaxf(tm, __shfl_xor(tm, m, 64));
      const float mnew = fmaxf(mrow[r], tm);
      const float fs = __expf(mrow[r] - mnew);
      mrow[r] = mnew;
      float psum = 0.0f;
      #pragma unroll
      for (int fn = 0; fn < 4; ++fn) {
        float pp = __expf(sacc[fn][r] - mnew);
        sacc[fn][r] = pp;
        psum += pp;
      }
      #pragma unroll
      for (int m = 1; m <= 8; m <<= 1) psum += __shfl_xor(psum, m, 64);
      lrow[r] = lrow[r] * fs + psum;
      #pragma unroll
      for (int fd = 0; fd < 4; ++fd) oacc[fd][r] *= fs;
    }

    // spill P (C-layout) to LDS as bf16, reread in A-layout
    {
      const int pr = (lane >> 4) * 4;
      #pragma unroll
      for (int fn = 0; fn < 4; ++fn)
        #pragma unroll
        for (int r = 0; r < 4; ++r)
          Ps[w][(pr + r) * 64 + fn * 16 + (lane & 15)] = f2b(sacc[fn][r]);
    }
    #pragma unroll
    for (int ks = 0; ks < 2; ++ks) {
      bf16x8 pa = *(const bf16x8*)&Ps[w][(lane & 15) * 64 + ks * 32 + ko];
      #pragma unroll
      for (int fd = 0; fd < 4; ++fd) {
        bf16x8 vbf = *(const bf16x8*)&Vts[(fd * 16 + (lane & 15)) * 64 + ks * 32 + ko];
        oacc[fd] = __builtin_amdgcn_mfma_f32_16x16x32_bf16(pa, vbf, oacc[fd], 0, 0, 0);
      }
    }
    __syncthreads();
  }

  #pragma unroll
  for (int fd = 0; fd < 4; ++fd)
    #pragma unroll
    for (int r = 0; r < 4; ++r) {
      const int row = q0 + (lane >> 4) * 4 + r;
      const float v = oacc[fd][r] / lrow[r];
      O[base + (size_t)row * DM + fd * 16 + (lane & 15)] = f2b(v);
    }
}

// ---------------------------------------------------------------------------
extern "C" void kernel_launch(void* const* d_in, const int* in_sizes, int n_in,
                              void* d_out, int out_size, void* d_ws, size_t ws_size,
                              hipStream_t stream) {
  const float* x    = (const float*)d_in[0];
  const float* Wq   = (const float*)d_in[1];
  const float* bq   = (const float*)d_in[2];
  const float* Wk   = (const float*)d_in[3];
  const float* bk   = (const float*)d_in[4];
  const float* Wv   = (const float*)d_in[5];
  const float* bv   = (const float*)d_in[6];
  const float* Wo   = (const float*)d_in[7];
  const float* bo   = (const float*)d_in[8];
  const float* ln1g = (const float*)d_in[9];
  const float* ln1b = (const float*)d_in[10];
  const float* W1   = (const float*)d_in[11];
  const float* b1   = (const float*)d_in[12];
  const float* W2   = (const float*)d_in[13];
  const float* b2   = (const float*)d_in[14];
  const float* ln2g = (const float*)d_in[15];
  const float* ln2b = (const float*)d_in[16];
  float* out = (float*)d_out;

  char* wsb = (char*)d_ws;
  size_t off = 0;
  auto alloc = [&](size_t bytes) -> char* {
    char* pp = wsb + off;
    off += (bytes + 255) & ~(size_t)255;
    return pp;
  };
  u16* Wq_b = (u16*)alloc((size_t)DM * DM * 2);
  u16* Wk_b = (u16*)alloc((size_t)DM * DM * 2);
  u16* Wv_b = (u16*)alloc((size_t)DM * DM * 2);
  u16* Wo_b = (u16*)alloc((size_t)DM * DM * 2);
  u16* W1_b = (u16*)alloc((size_t)DFF * DM * 2);
  u16* W2_b = (u16*)alloc((size_t)DM * DFF * 2);
  u16* xn   = (u16*)alloc((size_t)MROWS * DM * 2);
  u16* qb   = (u16*)alloc((size_t)MROWS * DM * 2);
  u16* kb   = (u16*)alloc((size_t)MROWS * DM * 2);
  u16* vb   = (u16*)alloc((size_t)MROWS * DM * 2);
  u16* ao   = (u16*)alloc((size_t)MROWS * DM * 2);
  u16* h1   = (u16*)alloc((size_t)MROWS * DFF * 2);

  // 1. convert weights to bf16
  CvtArgs ca;
  ca.src[0] = Wq; ca.dst[0] = Wq_b; ca.n4[0] = DM * DM / 4;
  ca.src[1] = Wk; ca.dst[1] = Wk_b; ca.n4[1] = DM * DM / 4;
  ca.src[2] = Wv; ca.dst[2] = Wv_b; ca.n4[2] = DM * DM / 4;
  ca.src[3] = Wo; ca.dst[3] = Wo_b; ca.n4[3] = DM * DM / 4;
  ca.src[4] = W1; ca.dst[4] = W1_b; ca.n4[4] = DFF * DM / 4;
  ca.src[5] = W2; ca.dst[5] = W2_b; ca.n4[5] = DM * DFF / 4;
  cvt_kernel<<<2048, 256, 0, stream>>>(ca);

  // 2. LN1
  ln_kernel<<<MROWS, 256, 0, stream>>>(x, ln1g, ln1b, xn);

  // 3. QKV projections (fused via blockIdx.z)
  GemmPtrs pq = {};
  pq.W[0] = Wq_b; pq.W[1] = Wk_b; pq.W[2] = Wv_b;
  pq.bias[0] = bq; pq.bias[1] = bk; pq.bias[2] = bv;
  pq.out[0] = qb; pq.out[1] = kb; pq.out[2] = vb;
  gemm_bt<0><<<dim3(DM / 128, MROWS / 128, 3), 256, 0, stream>>>(xn, pq, MROWS, DM, DM);

  // 4. attention
  attn_kernel<<<dim3(SEQ / 64, 2 * NH), 256, 0, stream>>>(qb, kb, vb, ao);

  // 5. output projection + residual -> d_out (fp32)
  GemmPtrs po = {};
  po.W[0] = Wo_b; po.bias[0] = bo; po.out[0] = out; po.resid = x;
  gemm_bt<2><<<dim3(DM / 128, MROWS / 128, 1), 256, 0, stream>>>(ao, po, MROWS, DM, DM);

  // 6. LN2 on x1 (= d_out)
  ln_kernel<<<MROWS, 256, 0, stream>>>(out, ln2g, ln2b, xn);

  // 7. FFN up + GELU
  GemmPtrs p1 = {};
  p1.W[0] = W1_b; p1.bias[0] = b1; p1.out[0] = h1;
  gemm_bt<1><<<dim3(DFF / 128, MROWS / 128, 1), 256, 0, stream>>>(xn, p1, MROWS, DFF, DM);

  // 8. FFN down + residual (in-place read/write of d_out by same thread)
  GemmPtrs p2 = {};
  p2.W[0] = W2_b; p2.bias[0] = b2; p2.out[0] = out; p2.resid = out;
  gemm_bt<2><<<dim3(DM / 128, MROWS / 128, 1), 256, 0, stream>>>(h1, p2, MROWS, DM, DFF);
}

// Round 2
// 423.131 us; speedup vs baseline: 1.1156x; 1.1156x over previous
//
#include <hip/hip_runtime.h>
#include <stdint.h>

#define DM 1024
#define DFF 4096
#define NH 16
#define DH 64
#define SEQ 2048
#define MROWS 4096  // B*S

typedef unsigned short u16;
typedef __attribute__((ext_vector_type(8))) short bf16x8;
typedef __attribute__((ext_vector_type(4))) float f32x4;
typedef __attribute__((ext_vector_type(4))) unsigned short u16x4;

__device__ __forceinline__ u16 f2b(float f) {
  union { float f; uint32_t u; } v; v.f = f;
  uint32_t r = v.u + 0x7FFFu + ((v.u >> 16) & 1u);
  return (u16)(r >> 16);
}

__device__ __forceinline__ void gl_lds16(const void* g, void* l) {
  __builtin_amdgcn_global_load_lds(
      (const __attribute__((address_space(1))) uint32_t*)g,
      (__attribute__((address_space(3))) uint32_t*)l, 16, 0, 0);
}

// ---------------- weight fp32 -> bf16 convert (all 6 weights, one kernel) --
struct CvtArgs { const float* src[6]; u16* dst[6]; int n4[6]; };

__global__ void cvt_kernel(CvtArgs a) {
  const int stride = gridDim.x * blockDim.x;
  const int t0 = blockIdx.x * blockDim.x + threadIdx.x;
  for (int i = 0; i < 6; ++i) {
    const float4* s = (const float4*)a.src[i];
    u16x4* d = (u16x4*)a.dst[i];
    const int n = a.n4[i];
    for (int idx = t0; idx < n; idx += stride) {
      float4 v = s[idx];
      u16x4 o;
      o[0] = f2b(v.x); o[1] = f2b(v.y); o[2] = f2b(v.z); o[3] = f2b(v.w);
      d[idx] = o;
    }
  }
}

// ---------------- fused LayerNorm: fp32 in -> bf16 out ---------------------
__global__ __launch_bounds__(256)
void ln_kernel(const float* __restrict__ x, const float* __restrict__ g,
               const float* __restrict__ be, u16* __restrict__ out) {
  const int row = blockIdx.x;
  const int tid = threadIdx.x;
  const float4 v = ((const float4*)(x + (size_t)row * DM))[tid];
  float s  = v.x + v.y + v.z + v.w;
  float s2 = v.x * v.x + v.y * v.y + v.z * v.z + v.w * v.w;
  #pragma unroll
  for (int m = 1; m < 64; m <<= 1) {
    s  += __shfl_xor(s,  m, 64);
    s2 += __shfl_xor(s2, m, 64);
  }
  __shared__ float red[8];
  const int w = tid >> 6, lane = tid & 63;
  if (lane == 0) { red[w] = s; red[4 + w] = s2; }
  __syncthreads();
  s  = red[0] + red[1] + red[2] + red[3];
  s2 = red[4] + red[5] + red[6] + red[7];
  const float mu  = s * (1.0f / DM);
  const float var = s2 * (1.0f / DM) - mu * mu;
  const float rstd = rsqrtf(var + 1e-5f);
  const float4 gv = ((const float4*)g)[tid];
  const float4 bv = ((const float4*)be)[tid];
  u16x4 o;
  o[0] = f2b((v.x - mu) * rstd * gv.x + bv.x);
  o[1] = f2b((v.y - mu) * rstd * gv.y + bv.y);
  o[2] = f2b((v.z - mu) * rstd * gv.z + bv.z);
  o[3] = f2b((v.w - mu) * rstd * gv.w + bv.w);
  ((u16x4*)(out + (size_t)row * DM))[tid] = o;
}

// ---------------- GEMM: C[M,N] = A[M,K](bf16) * W[N,K](bf16)^T + bias ------
// EPI 0: -> bf16 (z==2 + vtrans: write transposed [b*DM+col][SEQ])
// EPI 1: +GELU(exact) -> bf16      EPI 2: +resid -> f32
struct GemmPtrs { const u16* W[3]; const float* bias[3]; void* out[3];
                  const float* resid; int vtrans; };

template<int EPI>
__global__ __launch_bounds__(256)
void gemm_bt(const u16* __restrict__ A, GemmPtrs p, int M, int N, int K) {
  __shared__ __align__(16) u16 As[128 * 64];
  __shared__ __align__(16) u16 Bs[128 * 64];
  const u16* __restrict__ Wm = p.W[blockIdx.z];
  const float* __restrict__ bias = p.bias[blockIdx.z];
  void* outv = p.out[blockIdx.z];
  const float* resid = p.resid;

  const int tid = threadIdx.x;
  const int lane = tid & 63;
  const int w = tid >> 6;
  const int brow = blockIdx.y * 128;
  const int bcol = blockIdx.x * 128;
  const int wr = (w >> 1) * 64, wc = (w & 1) * 64;

  f32x4 acc[4][4] = {};

  const int srow = lane >> 3;           // staging row within 8-row group
  const int scol = (lane & 7) * 8;      // staging col (bf16 elements)
  const int nkt = K >> 6;
  for (int kt = 0; kt < nkt; ++kt) {
    const int k0 = kt * 64;
    #pragma unroll
    for (int i = 0; i < 4; ++i) {
      const int r = i * 32 + w * 8;
      gl_lds16(&A [(size_t)(brow + r + srow) * K + k0 + scol], &As[r * 64]);
      gl_lds16(&Wm[(size_t)(bcol + r + srow) * K + k0 + scol], &Bs[r * 64]);
    }
    __syncthreads();
    #pragma unroll
    for (int ks = 0; ks < 2; ++ks) {
      const int ko = ks * 32 + (lane >> 4) * 8;
      bf16x8 a[4], b[4];
      #pragma unroll
      for (int f = 0; f < 4; ++f)
        a[f] = *(const bf16x8*)&As[(wr + f * 16 + (lane & 15)) * 64 + ko];
      #pragma unroll
      for (int f = 0; f < 4; ++f)
        b[f] = *(const bf16x8*)&Bs[(wc + f * 16 + (lane & 15)) * 64 + ko];
      #pragma unroll
      for (int fr = 0; fr < 4; ++fr)
        #pragma unroll
        for (int fc = 0; fc < 4; ++fc)
          acc[fr][fc] = __builtin_amdgcn_mfma_f32_16x16x32_bf16(a[fr], b[fc], acc[fr][fc], 0, 0, 0);
    }
    __syncthreads();
  }

  const int orow0 = brow + wr + (lane >> 4) * 4;
  const int ocol0 = bcol + wc + (lane & 15);

  if (EPI == 0 && p.vtrans && blockIdx.z == 2) {
    // V projection written transposed: Vt[(b*DM + col)][s], s = row % SEQ
    #pragma unroll
    for (int fr = 0; fr < 4; ++fr) {
      const int row0 = orow0 + fr * 16;
      const int bq = row0 >> 11, s0 = row0 & (SEQ - 1);
      #pragma unroll
      for (int fc = 0; fc < 4; ++fc) {
        const int col = ocol0 + fc * 16;
        const float bvv = bias[col];
        u16x4 o;
        #pragma unroll
        for (int r = 0; r < 4; ++r) o[r] = f2b(acc[fr][fc][r] + bvv);
        *(u16x4*)((u16*)outv + (size_t)(bq * DM + col) * SEQ + s0) = o;
      }
    }
    return;
  }

  #pragma unroll
  for (int fr = 0; fr < 4; ++fr) {
    #pragma unroll
    for (int fc = 0; fc < 4; ++fc) {
      const int col = ocol0 + fc * 16;
      const float bvv = bias[col];
      #pragma unroll
      for (int r = 0; r < 4; ++r) {
        const int row = orow0 + fr * 16 + r;
        const size_t idx = (size_t)row * N + col;
        float v = acc[fr][fc][r] + bvv;
        if (EPI == 0) {
          ((u16*)outv)[idx] = f2b(v);
        } else if (EPI == 1) {
          float ge = 0.5f * v * (1.0f + erff(v * 0.70710678118654752f));
          ((u16*)outv)[idx] = f2b(ge);
        } else {
          ((float*)outv)[idx] = v + resid[idx];
        }
      }
    }
  }
}

// ---------------- flash attention: Q,K [B,S,H*DH]; Vt [(b*DM+h*DH+d)][s] ---
__global__ __launch_bounds__(256)
void attn_kernel(const u16* __restrict__ Q, const u16* __restrict__ K,
                 const u16* __restrict__ Vt, u16* __restrict__ O) {
  __shared__ __align__(16) u16 Ks[64 * 64];
  __shared__ __align__(16) u16 Vts[64 * 64];   // [d][key] staged linearly
  __shared__ __align__(16) u16 Ps[4][16 * 64]; // per-wave P tile
  const int tid = threadIdx.x, lane = tid & 63, w = tid >> 6;
  const int bh = blockIdx.y, b = bh >> 4, h = bh & 15;
  const int q0 = blockIdx.x * 64 + w * 16;     // wave's q-row base in seq
  const size_t base = (size_t)b * SEQ * DM + (size_t)h * DH;
  const size_t vbase = (size_t)(b * DM + h * DH) * SEQ;  // Vt row-major [d][s]

  // Q fragments (A-layout): row = lane&15, k = ks*32 + (lane>>4)*8
  bf16x8 qf[2];
  {
    const size_t qrow = base + (size_t)(q0 + (lane & 15)) * DM;
    #pragma unroll
    for (int ks = 0; ks < 2; ++ks)
      qf[ks] = *(const bf16x8*)&Q[qrow + ks * 32 + (lane >> 4) * 8];
  }

  f32x4 oacc[4] = {};
  float mrow[4], lrow[4];
  #pragma unroll
  for (int r = 0; r < 4; ++r) { mrow[r] = -1e30f; lrow[r] = 0.0f; }

  const int srow = lane >> 3, scol = (lane & 7) * 8;
  const int ko = (lane >> 4) * 8;

  for (int kt = 0; kt < SEQ / 64; ++kt) {
    // stage K tile (64x64) and Vt tile (64x64) linearly via global_load_lds
    #pragma unroll
    for (int i = 0; i < 2; ++i) {
      const int r = i * 32 + w * 8;
      gl_lds16(&K[base + (size_t)(kt * 64 + r + srow) * DM + scol], &Ks[r * 64]);
      gl_lds16(&Vt[vbase + (size_t)(r + srow) * SEQ + kt * 64 + scol], &Vts[r * 64]);
    }
    __syncthreads();

    // S = Q K^T  (scaled later)
    f32x4 sacc[4] = {};
    #pragma unroll
    for (int ks = 0; ks < 2; ++ks) {
      #pragma unroll
      for (int fn = 0; fn < 4; ++fn) {
        bf16x8 kb = *(const bf16x8*)&Ks[(fn * 16 + (lane & 15)) * 64 + ks * 32 + ko];
        sacc[fn] = __builtin_amdgcn_mfma_f32_16x16x32_bf16(qf[ks], kb, sacc[fn], 0, 0, 0);
      }
    }
    #pragma unroll
    for (int fn = 0; fn < 4; ++fn) sacc[fn] *= 0.125f;  // 1/sqrt(64)

    // online softmax update (rows r; 16-lane col-group reductions)
    #pragma unroll
    for (int r = 0; r < 4; ++r) {
      float tm = fmaxf(fmaxf(sacc[0][r], sacc[1][r]), fmaxf(sacc[2][r], sacc[3][r]));
      #pragma unroll
      for (int m = 1; m <= 8; m <<= 1) tm = fmaxf(tm, __shfl_xor(tm, m, 64));
      const float mnew = fmaxf(mrow[r], tm);
      const float fs = __expf(mrow[r] - mnew);
      mrow[r] = mnew;
      float psum = 0.0f;
      #pragma unroll
      for (int fn = 0; fn < 4; ++fn) {
        float pp = __expf(sacc[fn][r] - mnew);
        sacc[fn][r] = pp;
        psum += pp;
      }
      #pragma unroll
      for (int m = 1; m <= 8; m <<= 1) psum += __shfl_xor(psum, m, 64);
      lrow[r] = lrow[r] * fs + psum;
      #pragma unroll
      for (int fd = 0; fd < 4; ++fd) oacc[fd][r] *= fs;
    }

    // spill P (C-layout) to LDS as bf16, reread in A-layout
    {
      const int pr = (lane >> 4) * 4;
      #pragma unroll
      for (int fn = 0; fn < 4; ++fn)
        #pragma unroll
        for (int r = 0; r < 4; ++r)
          Ps[w][(pr + r) * 64 + fn * 16 + (lane & 15)] = f2b(sacc[fn][r]);
    }
    #pragma unroll
    for (int ks = 0; ks < 2; ++ks) {
      bf16x8 pa = *(const bf16x8*)&Ps[w][(lane & 15) * 64 + ks * 32 + ko];
      #pragma unroll
      for (int fd = 0; fd < 4; ++fd) {
        bf16x8 vbf = *(const bf16x8*)&Vts[(fd * 16 + (lane & 15)) * 64 + ks * 32 + ko];
        oacc[fd] = __builtin_amdgcn_mfma_f32_16x16x32_bf16(pa, vbf, oacc[fd], 0, 0, 0);
      }
    }
    __syncthreads();
  }

  #pragma unroll
  for (int fd = 0; fd < 4; ++fd)
    #pragma unroll
    for (int r = 0; r < 4; ++r) {
      const int row = q0 + (lane >> 4) * 4 + r;
      const float v = oacc[fd][r] / lrow[r];
      O[base + (size_t)row * DM + fd * 16 + (lane & 15)] = f2b(v);
    }
}

// ---------------------------------------------------------------------------
extern "C" void kernel_launch(void* const* d_in, const int* in_sizes, int n_in,
                              void* d_out, int out_size, void* d_ws, size_t ws_size,
                              hipStream_t stream) {
  const float* x    = (const float*)d_in[0];
  const float* Wq   = (const float*)d_in[1];
  const float* bq   = (const float*)d_in[2];
  const float* Wk   = (const float*)d_in[3];
  const float* bk   = (const float*)d_in[4];
  const float* Wv   = (const float*)d_in[5];
  const float* bv   = (const float*)d_in[6];
  const float* Wo   = (const float*)d_in[7];
  const float* bo   = (const float*)d_in[8];
  const float* ln1g = (const float*)d_in[9];
  const float* ln1b = (const float*)d_in[10];
  const float* W1   = (const float*)d_in[11];
  const float* b1   = (const float*)d_in[12];
  const float* W2   = (const float*)d_in[13];
  const float* b2   = (const float*)d_in[14];
  const float* ln2g = (const float*)d_in[15];
  const float* ln2b = (const float*)d_in[16];
  float* out = (float*)d_out;

  char* wsb = (char*)d_ws;
  size_t off = 0;
  auto alloc = [&](size_t bytes) -> char* {
    char* pp = wsb + off;
    off += (bytes + 255) & ~(size_t)255;
    return pp;
  };
  u16* Wq_b = (u16*)alloc((size_t)DM * DM * 2);
  u16* Wk_b = (u16*)alloc((size_t)DM * DM * 2);
  u16* Wv_b = (u16*)alloc((size_t)DM * DM * 2);
  u16* Wo_b = (u16*)alloc((size_t)DM * DM * 2);
  u16* W1_b = (u16*)alloc((size_t)DFF * DM * 2);
  u16* W2_b = (u16*)alloc((size_t)DM * DFF * 2);
  u16* xn   = (u16*)alloc((size_t)MROWS * DM * 2);
  u16* qb   = (u16*)alloc((size_t)MROWS * DM * 2);
  u16* kb   = (u16*)alloc((size_t)MROWS * DM * 2);
  u16* vt   = (u16*)alloc((size_t)MROWS * DM * 2);  // transposed V
  u16* ao   = (u16*)alloc((size_t)MROWS * DM * 2);
  u16* h1   = (u16*)alloc((size_t)MROWS * DFF * 2);

  // 1. convert weights to bf16
  CvtArgs ca;
  ca.src[0] = Wq; ca.dst[0] = Wq_b; ca.n4[0] = DM * DM / 4;
  ca.src[1] = Wk; ca.dst[1] = Wk_b; ca.n4[1] = DM * DM / 4;
  ca.src[2] = Wv; ca.dst[2] = Wv_b; ca.n4[2] = DM * DM / 4;
  ca.src[3] = Wo; ca.dst[3] = Wo_b; ca.n4[3] = DM * DM / 4;
  ca.src[4] = W1; ca.dst[4] = W1_b; ca.n4[4] = DFF * DM / 4;
  ca.src[5] = W2; ca.dst[5] = W2_b; ca.n4[5] = DM * DFF / 4;
  cvt_kernel<<<2048, 256, 0, stream>>>(ca);

  // 2. LN1
  ln_kernel<<<MROWS, 256, 0, stream>>>(x, ln1g, ln1b, xn);

  // 3. QKV projections (fused via blockIdx.z; V written transposed)
  GemmPtrs pq = {};
  pq.W[0] = Wq_b; pq.W[1] = Wk_b; pq.W[2] = Wv_b;
  pq.bias[0] = bq; pq.bias[1] = bk; pq.bias[2] = bv;
  pq.out[0] = qb; pq.out[1] = kb; pq.out[2] = vt;
  pq.vtrans = 1;
  gemm_bt<0><<<dim3(DM / 128, MROWS / 128, 3), 256, 0, stream>>>(xn, pq, MROWS, DM, DM);

  // 4. attention
  attn_kernel<<<dim3(SEQ / 64, 2 * NH), 256, 0, stream>>>(qb, kb, vt, ao);

  // 5. output projection + residual -> d_out (fp32)
  GemmPtrs po = {};
  po.W[0] = Wo_b; po.bias[0] = bo; po.out[0] = out; po.resid = x;
  gemm_bt<2><<<dim3(DM / 128, MROWS / 128, 1), 256, 0, stream>>>(ao, po, MROWS, DM, DM);

  // 6. LN2 on x1 (= d_out)
  ln_kernel<<<MROWS, 256, 0, stream>>>(out, ln2g, ln2b, xn);

  // 7. FFN up + GELU
  GemmPtrs p1 = {};
  p1.W[0] = W1_b; p1.bias[0] = b1; p1.out[0] = h1;
  gemm_bt<1><<<dim3(DFF / 128, MROWS / 128, 1), 256, 0, stream>>>(xn, p1, MROWS, DFF, DM);

  // 8. FFN down + residual (in-place read/write of d_out by same thread)
  GemmPtrs p2 = {};
  p2.W[0] = W2_b; p2.bias[0] = b2; p2.out[0] = out; p2.resid = out;
  gemm_bt<2><<<dim3(DM / 128, MROWS / 128, 1), 256, 0, stream>>>(h1, p2, MROWS, DM, DFF);
}

// Round 3
// 343.875 us; speedup vs baseline: 1.3727x; 1.2305x over previous
//
#include <hip/hip_runtime.h>
#include <stdint.h>

#define DM 1024
#define DFF 4096
#define NH 16
#define DH 64
#define SEQ 2048
#define MROWS 4096  // B*S

typedef unsigned short u16;
typedef __attribute__((ext_vector_type(8))) short bf16x8;
typedef __attribute__((ext_vector_type(4))) float f32x4;
typedef __attribute__((ext_vector_type(4))) unsigned short u16x4;

__device__ __forceinline__ u16 f2b(float f) {
  union { float f; uint32_t u; } v; v.f = f;
  uint32_t r = v.u + 0x7FFFu + ((v.u >> 16) & 1u);
  return (u16)(r >> 16);
}

__device__ __forceinline__ void gl_lds16(const void* g, void* l) {
  __builtin_amdgcn_global_load_lds(
      (const __attribute__((address_space(1))) uint32_t*)g,
      (__attribute__((address_space(3))) uint32_t*)l, 16, 0, 0);
}

// ---------------- weight fp32 -> bf16 convert (all 6 weights, one kernel) --
struct CvtArgs { const float* src[6]; u16* dst[6]; int n4[6]; };

__global__ void cvt_kernel(CvtArgs a) {
  const int stride = gridDim.x * blockDim.x;
  const int t0 = blockIdx.x * blockDim.x + threadIdx.x;
  for (int i = 0; i < 6; ++i) {
    const float4* s = (const float4*)a.src[i];
    u16x4* d = (u16x4*)a.dst[i];
    const int n = a.n4[i];
    for (int idx = t0; idx < n; idx += stride) {
      float4 v = s[idx];
      u16x4 o;
      o[0] = f2b(v.x); o[1] = f2b(v.y); o[2] = f2b(v.z); o[3] = f2b(v.w);
      d[idx] = o;
    }
  }
}

// ---------------- fused LayerNorm: fp32 in -> bf16 out ---------------------
__global__ __launch_bounds__(256)
void ln_kernel(const float* __restrict__ x, const float* __restrict__ g,
               const float* __restrict__ be, u16* __restrict__ out) {
  const int row = blockIdx.x;
  const int tid = threadIdx.x;
  const float4 v = ((const float4*)(x + (size_t)row * DM))[tid];
  float s  = v.x + v.y + v.z + v.w;
  float s2 = v.x * v.x + v.y * v.y + v.z * v.z + v.w * v.w;
  #pragma unroll
  for (int m = 1; m < 64; m <<= 1) {
    s  += __shfl_xor(s,  m, 64);
    s2 += __shfl_xor(s2, m, 64);
  }
  __shared__ float red[8];
  const int w = tid >> 6, lane = tid & 63;
  if (lane == 0) { red[w] = s; red[4 + w] = s2; }
  __syncthreads();
  s  = red[0] + red[1] + red[2] + red[3];
  s2 = red[4] + red[5] + red[6] + red[7];
  const float mu  = s * (1.0f / DM);
  const float var = s2 * (1.0f / DM) - mu * mu;
  const float rstd = rsqrtf(var + 1e-5f);
  const float4 gv = ((const float4*)g)[tid];
  const float4 bv = ((const float4*)be)[tid];
  u16x4 o;
  o[0] = f2b((v.x - mu) * rstd * gv.x + bv.x);
  o[1] = f2b((v.y - mu) * rstd * gv.y + bv.y);
  o[2] = f2b((v.z - mu) * rstd * gv.z + bv.z);
  o[3] = f2b((v.w - mu) * rstd * gv.w + bv.w);
  ((u16x4*)(out + (size_t)row * DM))[tid] = o;
}

// ---------------- combine: out = p0 + p1 + bias + resid (fp32) -------------
__global__ __launch_bounds__(256)
void combine_kernel(const float4* __restrict__ p0, const float4* __restrict__ p1,
                    const float4* __restrict__ bias, const float4* __restrict__ resid,
                    float4* __restrict__ out, int total4, int colmask4) {
  for (int i = blockIdx.x * 256 + threadIdx.x; i < total4; i += gridDim.x * 256) {
    float4 a = p0[i], b = p1[i], bs = bias[i & colmask4], rr = resid[i];
    float4 o;
    o.x = a.x + b.x + bs.x + rr.x;
    o.y = a.y + b.y + bs.y + rr.y;
    o.z = a.z + b.z + bs.z + rr.z;
    o.w = a.w + b.w + bs.w + rr.w;
    out[i] = o;
  }
}

// ---------------- GEMM: C[M,N] = A[M,K](bf16) * W[N,K](bf16)^T + bias ------
// EPI 0: -> bf16 (z==2 + vtrans: write transposed [b*DM+col][SEQ])
// EPI 1: +GELU(exact) -> bf16      EPI 2: +resid -> f32
// EPI 3: K-split partial, no bias -> f32 (z selects K-chunk + partial buffer)
struct GemmPtrs { const u16* W[3]; const float* bias[3]; void* out[3];
                  const float* resid; int vtrans; };

template<int EPI>
__global__ __launch_bounds__(256)
void gemm_bt(const u16* __restrict__ A, GemmPtrs p, int M, int N,
             int Kstride, int Kchunk) {
  __shared__ __align__(16) u16 As[128 * 64];
  __shared__ __align__(16) u16 Bs[128 * 64];
  const u16* __restrict__ Wm = p.W[blockIdx.z];
  const float* __restrict__ bias = p.bias[blockIdx.z];
  void* outv = p.out[blockIdx.z];
  const float* resid = p.resid;

  const int tid = threadIdx.x;
  const int lane = tid & 63;
  const int w = tid >> 6;
  const int brow = blockIdx.y * 128;
  const int bcol = blockIdx.x * 128;
  const int wr = (w >> 1) * 64, wc = (w & 1) * 64;
  const int koff = (EPI == 3) ? blockIdx.z * Kchunk : 0;

  f32x4 acc[4][4] = {};

  const int srow = lane >> 3;           // staging row within 8-row group
  const int scol = (lane & 7) * 8;      // staging col (bf16 elements)
  const int nkt = Kchunk >> 6;
  for (int kt = 0; kt < nkt; ++kt) {
    const int k0 = koff + kt * 64;
    #pragma unroll
    for (int i = 0; i < 4; ++i) {
      const int r = i * 32 + w * 8;
      gl_lds16(&A [(size_t)(brow + r + srow) * Kstride + k0 + scol], &As[r * 64]);
      gl_lds16(&Wm[(size_t)(bcol + r + srow) * Kstride + k0 + scol], &Bs[r * 64]);
    }
    __syncthreads();
    #pragma unroll
    for (int ks = 0; ks < 2; ++ks) {
      const int ko = ks * 32 + (lane >> 4) * 8;
      bf16x8 a[4], b[4];
      #pragma unroll
      for (int f = 0; f < 4; ++f)
        a[f] = *(const bf16x8*)&As[(wr + f * 16 + (lane & 15)) * 64 + ko];
      #pragma unroll
      for (int f = 0; f < 4; ++f)
        b[f] = *(const bf16x8*)&Bs[(wc + f * 16 + (lane & 15)) * 64 + ko];
      #pragma unroll
      for (int fr = 0; fr < 4; ++fr)
        #pragma unroll
        for (int fc = 0; fc < 4; ++fc)
          acc[fr][fc] = __builtin_amdgcn_mfma_f32_16x16x32_bf16(a[fr], b[fc], acc[fr][fc], 0, 0, 0);
    }
    __syncthreads();
  }

  const int orow0 = brow + wr + (lane >> 4) * 4;
  const int ocol0 = bcol + wc + (lane & 15);

  if (EPI == 0 && p.vtrans && blockIdx.z == 2) {
    // V projection written transposed: Vt[(b*DM + col)][s], s = row % SEQ
    #pragma unroll
    for (int fr = 0; fr < 4; ++fr) {
      const int row0 = orow0 + fr * 16;
      const int bq = row0 >> 11, s0 = row0 & (SEQ - 1);
      #pragma unroll
      for (int fc = 0; fc < 4; ++fc) {
        const int col = ocol0 + fc * 16;
        const float bvv = bias[col];
        u16x4 o;
        #pragma unroll
        for (int r = 0; r < 4; ++r) o[r] = f2b(acc[fr][fc][r] + bvv);
        *(u16x4*)((u16*)outv + (size_t)(bq * DM + col) * SEQ + s0) = o;
      }
    }
    return;
  }

  #pragma unroll
  for (int fr = 0; fr < 4; ++fr) {
    #pragma unroll
    for (int fc = 0; fc < 4; ++fc) {
      const int col = ocol0 + fc * 16;
      const float bvv = (EPI == 3) ? 0.0f : bias[col];
      #pragma unroll
      for (int r = 0; r < 4; ++r) {
        const int row = orow0 + fr * 16 + r;
        const size_t idx = (size_t)row * N + col;
        float v = acc[fr][fc][r] + bvv;
        if (EPI == 0) {
          ((u16*)outv)[idx] = f2b(v);
        } else if (EPI == 1) {
          float ge = 0.5f * v * (1.0f + erff(v * 0.70710678118654752f));
          ((u16*)outv)[idx] = f2b(ge);
        } else if (EPI == 2) {
          ((float*)outv)[idx] = v + resid[idx];
        } else {
          ((float*)outv)[idx] = v;   // partial, bias added in combine
        }
      }
    }
  }
}

// ---------------- flash attention: Q,K [B,S,H*DH]; Vt [(b*DM+h*DH+d)][s] ---
// LDS tiles XOR-swizzled: LDS(row, chunk) = global(row, chunk ^ (row&7)),
// 16B chunks. Staging keeps LDS dest linear (global_load_lds) and applies
// the inverse permutation on the per-lane GLOBAL source (rule #21).
__global__ __launch_bounds__(256)
void attn_kernel(const u16* __restrict__ Q, const u16* __restrict__ K,
                 const u16* __restrict__ Vt, u16* __restrict__ O) {
  __shared__ __align__(16) u16 Ks[64 * 64];
  __shared__ __align__(16) u16 Vts[64 * 64];   // [d][key]
  __shared__ __align__(16) u16 Ps[4][16 * 64]; // per-wave P tile [q][k], swizzled
  const int tid = threadIdx.x, lane = tid & 63, w = tid >> 6;
  const int bh = blockIdx.y, b = bh >> 4, h = bh & 15;
  const int q0 = blockIdx.x * 64 + w * 16;     // wave's q-row base in seq
  const size_t base = (size_t)b * SEQ * DM + (size_t)h * DH;
  const size_t vbase = (size_t)(b * DM + h * DH) * SEQ;  // Vt row-major [d][s]

  const int l15 = lane & 15, hi = lane >> 4, l7 = lane & 7;
  // swizzled fragment k-offsets (elements) for ks=0/1: chunk = ks*4+hi, row&7 = l7
  const int kf[2] = { (hi ^ l7) * 8, ((4 + hi) ^ l7) * 8 };

  // Q fragments (A-layout): row = l15, k = ks*32 + hi*8
  bf16x8 qf[2];
  {
    const size_t qrow = base + (size_t)(q0 + l15) * DM;
    #pragma unroll
    for (int ks = 0; ks < 2; ++ks)
      qf[ks] = *(const bf16x8*)&Q[qrow + ks * 32 + hi * 8];
  }

  f32x4 oacc[4] = {};
  float mrow[4], lrow[4];
  #pragma unroll
  for (int r = 0; r < 4; ++r) { mrow[r] = -1e30f; lrow[r] = 0.0f; }

  const int srow = lane >> 3;
  const int scol_sw = ((lane & 7) ^ srow) * 8;   // inverse-swizzled global chunk

  for (int kt = 0; kt < SEQ / 64; ++kt) {
    // stage K tile and Vt tile (swizzled via pre-swizzled source)
    #pragma unroll
    for (int i = 0; i < 2; ++i) {
      const int r = i * 32 + w * 8;
      gl_lds16(&K[base + (size_t)(kt * 64 + r + srow) * DM + scol_sw], &Ks[r * 64]);
      gl_lds16(&Vt[vbase + (size_t)(r + srow) * SEQ + kt * 64 + scol_sw], &Vts[r * 64]);
    }
    __syncthreads();

    // S = Q K^T  (scaled later)
    f32x4 sacc[4] = {};
    __builtin_amdgcn_s_setprio(1);
    #pragma unroll
    for (int ks = 0; ks < 2; ++ks) {
      #pragma unroll
      for (int fn = 0; fn < 4; ++fn) {
        bf16x8 kb = *(const bf16x8*)&Ks[(fn * 16 + l15) * 64 + kf[ks]];
        sacc[fn] = __builtin_amdgcn_mfma_f32_16x16x32_bf16(qf[ks], kb, sacc[fn], 0, 0, 0);
      }
    }
    __builtin_amdgcn_s_setprio(0);
    #pragma unroll
    for (int fn = 0; fn < 4; ++fn) sacc[fn] *= 0.125f;  // 1/sqrt(64)

    // online softmax update (rows r = q; 16-lane col-group reductions)
    #pragma unroll
    for (int r = 0; r < 4; ++r) {
      float tm = fmaxf(fmaxf(sacc[0][r], sacc[1][r]), fmaxf(sacc[2][r], sacc[3][r]));
      #pragma unroll
      for (int m = 1; m <= 8; m <<= 1) tm = fmaxf(tm, __shfl_xor(tm, m, 64));
      const float mnew = fmaxf(mrow[r], tm);
      const float fs = __expf(mrow[r] - mnew);
      mrow[r] = mnew;
      float psum = 0.0f;
      #pragma unroll
      for (int fn = 0; fn < 4; ++fn) {
        float pp = __expf(sacc[fn][r] - mnew);
        sacc[fn][r] = pp;
        psum += pp;
      }
      #pragma unroll
      for (int m = 1; m <= 8; m <<= 1) psum += __shfl_xor(psum, m, 64);
      lrow[r] = lrow[r] * fs + psum;
      #pragma unroll
      for (int fd = 0; fd < 4; ++fd) oacc[fd][r] *= fs;
    }

    // spill P (C-layout: q=(hi*4+r), k=fn*16+l15) to LDS, swizzled
    {
      const int pr = hi * 4;
      #pragma unroll
      for (int fn = 0; fn < 4; ++fn)
        #pragma unroll
        for (int r = 0; r < 4; ++r) {
          const int q = pr + r;
          Ps[w][q * 64 + ((fn * 16 + l15) ^ ((q & 7) << 3))] = f2b(sacc[fn][r]);
        }
    }
    __builtin_amdgcn_s_setprio(1);
    #pragma unroll
    for (int ks = 0; ks < 2; ++ks) {
      bf16x8 pa = *(const bf16x8*)&Ps[w][l15 * 64 + kf[ks]];
      #pragma unroll
      for (int fd = 0; fd < 4; ++fd) {
        bf16x8 vbf = *(const bf16x8*)&Vts[(fd * 16 + l15) * 64 + kf[ks]];
        oacc[fd] = __builtin_amdgcn_mfma_f32_16x16x32_bf16(pa, vbf, oacc[fd], 0, 0, 0);
      }
    }
    __builtin_amdgcn_s_setprio(0);
    __syncthreads();
  }

  #pragma unroll
  for (int fd = 0; fd < 4; ++fd)
    #pragma unroll
    for (int r = 0; r < 4; ++r) {
      const int row = q0 + hi * 4 + r;
      const float v = oacc[fd][r] / lrow[r];
      O[base + (size_t)row * DM + fd * 16 + l15] = f2b(v);
    }
}

// ---------------------------------------------------------------------------
extern "C" void kernel_launch(void* const* d_in, const int* in_sizes, int n_in,
                              void* d_out, int out_size, void* d_ws, size_t ws_size,
                              hipStream_t stream) {
  const float* x    = (const float*)d_in[0];
  const float* Wq   = (const float*)d_in[1];
  const float* bq   = (const float*)d_in[2];
  const float* Wk   = (const float*)d_in[3];
  const float* bk   = (const float*)d_in[4];
  const float* Wv   = (const float*)d_in[5];
  const float* bv   = (const float*)d_in[6];
  const float* Wo   = (const float*)d_in[7];
  const float* bo   = (const float*)d_in[8];
  const float* ln1g = (const float*)d_in[9];
  const float* ln1b = (const float*)d_in[10];
  const float* W1   = (const float*)d_in[11];
  const float* b1   = (const float*)d_in[12];
  const float* W2   = (const float*)d_in[13];
  const float* b2   = (const float*)d_in[14];
  const float* ln2g = (const float*)d_in[15];
  const float* ln2b = (const float*)d_in[16];
  float* out = (float*)d_out;

  char* wsb = (char*)d_ws;
  size_t off = 0;
  auto alloc = [&](size_t bytes) -> char* {
    char* pp = wsb + off;
    off += (bytes + 255) & ~(size_t)255;
    return pp;
  };
  u16* Wq_b = (u16*)alloc((size_t)DM * DM * 2);
  u16* Wk_b = (u16*)alloc((size_t)DM * DM * 2);
  u16* Wv_b = (u16*)alloc((size_t)DM * DM * 2);
  u16* Wo_b = (u16*)alloc((size_t)DM * DM * 2);
  u16* W1_b = (u16*)alloc((size_t)DFF * DM * 2);
  u16* W2_b = (u16*)alloc((size_t)DM * DFF * 2);
  u16* xn   = (u16*)alloc((size_t)MROWS * DM * 2);
  u16* qb   = (u16*)alloc((size_t)MROWS * DM * 2);
  u16* kb   = (u16*)alloc((size_t)MROWS * DM * 2);
  u16* vt   = (u16*)alloc((size_t)MROWS * DM * 2);  // transposed V
  u16* ao   = (u16*)alloc((size_t)MROWS * DM * 2);
  u16* h1   = (u16*)alloc((size_t)MROWS * DFF * 2);

  // K-split partial buffers (fp32, 16 MB each) reuse dead regions:
  // pA = xn∪qb, pB = kb∪vt — dead during O-proj (after attn) and FFN2.
  float* pA = (float*)xn;
  float* pB = (float*)kb;

  // 1. convert weights to bf16
  CvtArgs ca;
  ca.src[0] = Wq; ca.dst[0] = Wq_b; ca.n4[0] = DM * DM / 4;
  ca.src[1] = Wk; ca.dst[1] = Wk_b; ca.n4[1] = DM * DM / 4;
  ca.src[2] = Wv; ca.dst[2] = Wv_b; ca.n4[2] = DM * DM / 4;
  ca.src[3] = Wo; ca.dst[3] = Wo_b; ca.n4[3] = DM * DM / 4;
  ca.src[4] = W1; ca.dst[4] = W1_b; ca.n4[4] = DFF * DM / 4;
  ca.src[5] = W2; ca.dst[5] = W2_b; ca.n4[5] = DM * DFF / 4;
  cvt_kernel<<<2048, 256, 0, stream>>>(ca);

  // 2. LN1
  ln_kernel<<<MROWS, 256, 0, stream>>>(x, ln1g, ln1b, xn);

  // 3. QKV projections (fused via blockIdx.z; V written transposed)
  GemmPtrs pq = {};
  pq.W[0] = Wq_b; pq.W[1] = Wk_b; pq.W[2] = Wv_b;
  pq.bias[0] = bq; pq.bias[1] = bk; pq.bias[2] = bv;
  pq.out[0] = qb; pq.out[1] = kb; pq.out[2] = vt;
  pq.vtrans = 1;
  gemm_bt<0><<<dim3(DM / 128, MROWS / 128, 3), 256, 0, stream>>>(xn, pq, MROWS, DM, DM, DM);

  // 4. attention
  attn_kernel<<<dim3(SEQ / 64, 2 * NH), 256, 0, stream>>>(qb, kb, vt, ao);

  // 5. output projection, K-split x2 -> partials, then combine(+bias+x) -> d_out
  GemmPtrs po = {};
  po.W[0] = Wo_b; po.W[1] = Wo_b;
  po.bias[0] = bo; po.bias[1] = bo;
  po.out[0] = pA; po.out[1] = pB;
  gemm_bt<3><<<dim3(DM / 128, MROWS / 128, 2), 256, 0, stream>>>(ao, po, MROWS, DM, DM, DM / 2);
  combine_kernel<<<2048, 256, 0, stream>>>((const float4*)pA, (const float4*)pB,
                                           (const float4*)bo, (const float4*)x,
                                           (float4*)out, MROWS * DM / 4, DM / 4 - 1);

  // 6. LN2 on x1 (= d_out)
  ln_kernel<<<MROWS, 256, 0, stream>>>(out, ln2g, ln2b, xn);

  // 7. FFN up + GELU
  GemmPtrs p1 = {};
  p1.W[0] = W1_b; p1.bias[0] = b1; p1.out[0] = h1;
  gemm_bt<1><<<dim3(DFF / 128, MROWS / 128, 1), 256, 0, stream>>>(xn, p1, MROWS, DFF, DM, DM);

  // 8. FFN down, K-split x2 -> partials, then combine(+bias+resid in place)
  GemmPtrs p2 = {};
  p2.W[0] = W2_b; p2.W[1] = W2_b;
  p2.bias[0] = b2; p2.bias[1] = b2;
  p2.out[0] = pA; p2.out[1] = pB;
  gemm_bt<3><<<dim3(DM / 128, MROWS / 128, 2), 256, 0, stream>>>(h1, p2, MROWS, DM, DFF, DFF / 2);
  combine_kernel<<<2048, 256, 0, stream>>>((const float4*)pA, (const float4*)pB,
                                           (const float4*)b2, (const float4*)out,
                                           (float4*)out, MROWS * DM / 4, DM / 4 - 1);
}